// Round 1
// baseline (128.197 us; speedup 1.0000x reference)
//
#include <hip/hip_runtime.h>
#include <hip/hip_bf16.h>
#include <stdint.h>

typedef uint16_t u16;
typedef float    f32x4  __attribute__((ext_vector_type(4)));
typedef __bf16   bf16x8 __attribute__((ext_vector_type(8)));
typedef uint16_t u16x8  __attribute__((ext_vector_type(8)));
typedef uint16_t u16x4  __attribute__((ext_vector_type(4)));

#define HH 16
#define SS 2048
#define EE 1024
#define DD 64

__device__ inline u16 f2bf(float f) {
  uint32_t u = __builtin_bit_cast(uint32_t, f);
  u += 0x7fff + ((u >> 16) & 1);   // RNE
  return (u16)(u >> 16);
}

__device__ inline void gload_lds16(const void* g, void* l) {
  __builtin_amdgcn_global_load_lds(
      (const __attribute__((address_space(1))) uint32_t*)g,
      (__attribute__((address_space(3))) uint32_t*)l, 16, 0, 0);
}

// ---------------- fp32 -> bf16 conversion of all inputs ----------------
__global__ __launch_bounds__(256) void convert_kernel(
    const float* __restrict__ x,  const float* __restrict__ wq,
    const float* __restrict__ wk, const float* __restrict__ wv,
    const float* __restrict__ wo,
    u16* __restrict__ xb, u16* __restrict__ wqkvb, u16* __restrict__ wob) {
  const int64_t M1 = 1024 * 1024;
  int64_t e = ((int64_t)blockIdx.x * 256 + threadIdx.x) * 4;   // 0 .. 6M
  const float* src; u16* dst; int64_t off;
  if (e < 2 * M1)      { src = x;  dst = xb;           off = e; }
  else if (e < 3 * M1) { src = wq; dst = wqkvb;        off = e - 2 * M1; }
  else if (e < 4 * M1) { src = wk; dst = wqkvb + M1;   off = e - 3 * M1; }
  else if (e < 5 * M1) { src = wv; dst = wqkvb + 2*M1; off = e - 4 * M1; }
  else                 { src = wo; dst = wob;          off = e - 5 * M1; }
  float4 v = *(const float4*)(src + off);
  u16x4 o;
  o[0] = f2bf(v.x); o[1] = f2bf(v.y); o[2] = f2bf(v.z); o[3] = f2bf(v.w);
  *(u16x4*)(dst + off) = o;
}

// ---------------- GEMM: C[M,N] = A[M,K] * B[N,K]^T (bf16 in, fp32 acc) --
// EPI 0: QKV projection -> scatter Q[H][S][D], K[H][S][D], V^T[H][D][S] (bf16)
// EPI 1: out-proj -> fp32 C row-major [M][N]
template <int EPI>
__global__ __launch_bounds__(256, 2) void gemm_kernel(
    const u16* __restrict__ A, const u16* __restrict__ B, int K, int N,
    u16* __restrict__ q_ws, u16* __restrict__ k_ws, u16* __restrict__ vt_ws,
    float* __restrict__ Cout) {
  constexpr int BM = 64, BN = 128, BK = 32;
  __shared__ __align__(16) u16 As[BM * BK];
  __shared__ __align__(16) u16 Bs[BN * BK];
  const int t = threadIdx.x;
  const int lane = t & 63, w = t >> 6;
  const int wr = w >> 1, wc = w & 1;          // 2x2 waves, each 32x64
  const int fr = lane & 15, fg = lane >> 4;
  const int m0 = blockIdx.y * BM, n0 = blockIdx.x * BN;

  f32x4 acc[2][4] = {};

  for (int k0 = 0; k0 < K; k0 += BK) {
    {
      const int c = t;                         // A: 64 rows x 64B = 256 chunks
      gload_lds16(A + (int64_t)(m0 + (c >> 2)) * K + k0 + (c & 3) * 8,
                  As + (c & ~63) * 8);
    }
#pragma unroll
    for (int it = 0; it < 2; ++it) {           // B: 128 rows = 512 chunks
      const int c = t + it * 256;
      gload_lds16(B + (int64_t)(n0 + (c >> 2)) * K + k0 + (c & 3) * 8,
                  Bs + (c & ~63) * 8);
    }
    __syncthreads();
    bf16x8 af[2], bfr[4];
#pragma unroll
    for (int mi = 0; mi < 2; ++mi)
      af[mi] = __builtin_bit_cast(
          bf16x8, *(const u16x8*)&As[(wr * 32 + mi * 16 + fr) * BK + fg * 8]);
#pragma unroll
    for (int ni = 0; ni < 4; ++ni)
      bfr[ni] = __builtin_bit_cast(
          bf16x8, *(const u16x8*)&Bs[(wc * 64 + ni * 16 + fr) * BK + fg * 8]);
#pragma unroll
    for (int mi = 0; mi < 2; ++mi)
#pragma unroll
      for (int ni = 0; ni < 4; ++ni)
        acc[mi][ni] = __builtin_amdgcn_mfma_f32_16x16x32_bf16(
            af[mi], bfr[ni], acc[mi][ni], 0, 0, 0);
    __syncthreads();
  }

#pragma unroll
  for (int mi = 0; mi < 2; ++mi)
#pragma unroll
    for (int ni = 0; ni < 4; ++ni)
#pragma unroll
      for (int r = 0; r < 4; ++r) {
        const int m = m0 + wr * 32 + mi * 16 + fg * 4 + r;  // C row
        const int n = n0 + wc * 64 + ni * 16 + fr;          // C col
        const float v = acc[mi][ni][r];
        if constexpr (EPI == 0) {
          const int which = n >> 10, nn = n & 1023, h = nn >> 6, d = nn & 63;
          const u16 bv = f2bf(v);
          if (which == 0)      q_ws[((int64_t)h * SS + m) * DD + d] = bv;
          else if (which == 1) k_ws[((int64_t)h * SS + m) * DD + d] = bv;
          else                 vt_ws[((int64_t)h * DD + d) * SS + m] = bv;
        } else {
          Cout[(int64_t)m * N + n] = v;
        }
      }
}

// ---------------- flash attention: per (head, 64-row q-block) ----------
__global__ __launch_bounds__(256, 2) void attn_kernel(
    const u16* __restrict__ q_ws, const u16* __restrict__ k_ws,
    const u16* __restrict__ vt_ws, u16* __restrict__ a_ws) {
  constexpr int QB = 64, KB = 64, LDP = 72;   // LDP: padded stride (bank-safe)
  __shared__ __align__(16) u16 Qs[QB * LDP];
  __shared__ __align__(16) u16 Ks[KB * LDP];
  __shared__ __align__(16) u16 Vs[DD * LDP];  // V^T tile: [v][key]
  __shared__ __align__(16) u16 Ps[4][16 * LDP];

  const int t = threadIdx.x;
  const int lane = t & 63, w = t >> 6;
  const int fr = lane & 15, fg = lane >> 4;
  const int h = blockIdx.y, qb = blockIdx.x;

  const u16* Qh = q_ws + ((int64_t)h * SS + qb * QB) * DD;
  const u16* Kh = k_ws + (int64_t)h * SS * DD;
  const u16* Vh = vt_ws + (int64_t)h * DD * SS;

#pragma unroll
  for (int it = 0; it < 2; ++it) {            // stage Q (64 rows x 128B)
    const int c = t + it * 256;
    const int row = c >> 3, ch = c & 7;
    *(u16x8*)&Qs[row * LDP + ch * 8] = *(const u16x8*)(Qh + row * DD + ch * 8);
  }
  __syncthreads();
  bf16x8 qf[2];                               // wave's 16 q-rows, hoisted
#pragma unroll
  for (int kc = 0; kc < 2; ++kc)
    qf[kc] = __builtin_bit_cast(
        bf16x8, *(const u16x8*)&Qs[(w * 16 + fr) * LDP + kc * 32 + fg * 8]);

  f32x4 o_acc[4] = {};
  float m_r[4], l_r[4];
#pragma unroll
  for (int r = 0; r < 4; ++r) { m_r[r] = -1e30f; l_r[r] = 0.f; }

  for (int kt = 0; kt < SS / KB; ++kt) {
    __syncthreads();                          // protect Ks/Vs from prev reads
#pragma unroll
    for (int it = 0; it < 2; ++it) {          // stage K tile + V^T tile
      const int c = t + it * 256;
      const int row = c >> 3, ch = c & 7;
      *(u16x8*)&Ks[row * LDP + ch * 8] =
          *(const u16x8*)(Kh + (int64_t)(kt * KB + row) * DD + ch * 8);
      *(u16x8*)&Vs[row * LDP + ch * 8] =
          *(const u16x8*)(Vh + (int64_t)row * SS + kt * KB + ch * 8);
    }
    __syncthreads();

    // S = Q K^T  (rows: q = fg*4+r, cols: key = c*16+fr)
    f32x4 s_acc[4] = {};
#pragma unroll
    for (int c = 0; c < 4; ++c)
#pragma unroll
      for (int kc = 0; kc < 2; ++kc) {
        bf16x8 kf = __builtin_bit_cast(
            bf16x8, *(const u16x8*)&Ks[(c * 16 + fr) * LDP + kc * 32 + fg * 8]);
        s_acc[c] =
            __builtin_amdgcn_mfma_f32_16x16x32_bf16(qf[kc], kf, s_acc[c], 0, 0, 0);
      }

    // online softmax (scale 1/8), per C-row r
    float p[4][4];
#pragma unroll
    for (int r = 0; r < 4; ++r) {
      float mx = fmaxf(fmaxf(s_acc[0][r], s_acc[1][r]),
                       fmaxf(s_acc[2][r], s_acc[3][r]));
#pragma unroll
      for (int off = 1; off < 16; off <<= 1) mx = fmaxf(mx, __shfl_xor(mx, off));
      mx *= 0.125f;
      const float mnew = fmaxf(m_r[r], mx);
      const float sf = __expf(m_r[r] - mnew);
      m_r[r] = mnew;
      float ls = 0.f;
#pragma unroll
      for (int c = 0; c < 4; ++c) {
        const float pv = __expf(s_acc[c][r] * 0.125f - mnew);
        p[c][r] = pv;
        ls += pv;
      }
#pragma unroll
      for (int off = 1; off < 16; off <<= 1) ls += __shfl_xor(ls, off);
      l_r[r] = l_r[r] * sf + ls;
#pragma unroll
      for (int n = 0; n < 4; ++n) o_acc[n][r] *= sf;
    }

    // P -> wave-private LDS (bf16), then read back as A-fragments
#pragma unroll
    for (int c = 0; c < 4; ++c)
#pragma unroll
      for (int r = 0; r < 4; ++r)
        Ps[w][(fg * 4 + r) * LDP + c * 16 + fr] = f2bf(p[c][r]);
    asm volatile("s_waitcnt lgkmcnt(0)" ::: "memory");

    // O += P * V   (B-frag from V^T rows: contiguous keys)
#pragma unroll
    for (int kc = 0; kc < 2; ++kc) {
      bf16x8 pf = __builtin_bit_cast(
          bf16x8, *(const u16x8*)&Ps[w][fr * LDP + kc * 32 + fg * 8]);
#pragma unroll
      for (int n = 0; n < 4; ++n) {
        bf16x8 vf = __builtin_bit_cast(
            bf16x8, *(const u16x8*)&Vs[(n * 16 + fr) * LDP + kc * 32 + fg * 8]);
        o_acc[n] = __builtin_amdgcn_mfma_f32_16x16x32_bf16(pf, vf, o_acc[n], 0, 0, 0);
      }
    }
  }

  // epilogue: A[q][h*64+v] bf16, normalized
#pragma unroll
  for (int n = 0; n < 4; ++n)
#pragma unroll
    for (int r = 0; r < 4; ++r) {
      const int q = qb * QB + w * 16 + fg * 4 + r;
      const int v = n * 16 + fr;
      a_ws[(int64_t)q * (HH * DD) + h * DD + v] = f2bf(o_acc[n][r] / l_r[r]);
    }
}

extern "C" void kernel_launch(void* const* d_in, const int* in_sizes, int n_in,
                              void* d_out, int out_size, void* d_ws, size_t ws_size,
                              hipStream_t stream) {
  const float* x  = (const float*)d_in[0];
  const float* wq = (const float*)d_in[1];
  const float* wk = (const float*)d_in[2];
  const float* wv = (const float*)d_in[3];
  const float* wo = (const float*)d_in[4];
  char* ws = (char*)d_ws;
  const int64_t Mi = 1 << 20;
  u16* xb   = (u16*)(ws + 0 * Mi);    // 4 MiB  (2M bf16)
  u16* wqkv = (u16*)(ws + 4 * Mi);    // 6 MiB  (3M bf16: Wq|Wk|Wv)
  u16* wob  = (u16*)(ws + 10 * Mi);   // 2 MiB
  u16* q_ws = (u16*)(ws + 12 * Mi);   // 4 MiB  [H][S][D]
  u16* k_ws = (u16*)(ws + 16 * Mi);   // 4 MiB  [H][S][D]
  u16* vt   = (u16*)(ws + 20 * Mi);   // 4 MiB  [H][D][S]
  u16* a_ws = (u16*)(ws + 24 * Mi);   // 4 MiB  [S][H*D]
  float* out = (float*)d_out;

  // 6M elements / 4 per thread / 256 per block
  convert_kernel<<<6144, 256, 0, stream>>>(x, wq, wk, wv, wo, xb, wqkv, wob);

  // QKV: [2048,1024] x [3072,1024]^T
  gemm_kernel<0><<<dim3(3072 / 128, 2048 / 64), 256, 0, stream>>>(
      xb, wqkv, 1024, 3072, q_ws, k_ws, vt, nullptr);

  attn_kernel<<<dim3(SS / 64, HH), 256, 0, stream>>>(q_ws, k_ws, vt, a_ws);

  // out-proj: [2048,1024] x [1024,1024]^T -> fp32
  gemm_kernel<1><<<dim3(1024 / 128, 2048 / 64), 256, 0, stream>>>(
      a_ws, wob, 1024, 1024, nullptr, nullptr, nullptr, out);
}

// Round 2
// 112.467 us; speedup vs baseline: 1.1399x; 1.1399x over previous
//
#include <hip/hip_runtime.h>
#include <hip/hip_bf16.h>
#include <stdint.h>

typedef uint16_t u16;
typedef uint32_t u32;
typedef float    f32x4  __attribute__((ext_vector_type(4)));
typedef __bf16   bf16x8 __attribute__((ext_vector_type(8)));
typedef uint16_t u16x8  __attribute__((ext_vector_type(8)));
typedef uint16_t u16x4  __attribute__((ext_vector_type(4)));
typedef uint32_t u32x4  __attribute__((ext_vector_type(4)));

#define HH 16
#define SS 2048
#define EE 1024
#define DD 64

__device__ inline u16 f2bf(float f) {
  uint32_t u = __builtin_bit_cast(uint32_t, f);
  u += 0x7fff + ((u >> 16) & 1);   // RNE
  return (u16)(u >> 16);
}

__device__ inline u32 cvtpk(float lo, float hi) {   // [15:0]=bf16(lo), [31:16]=bf16(hi)
  u32 r;
  asm("v_cvt_pk_bf16_f32 %0, %1, %2" : "=v"(r) : "v"(lo), "v"(hi));
  return r;
}

__device__ inline void gload_lds16(const void* g, void* l) {
  __builtin_amdgcn_global_load_lds(
      (const __attribute__((address_space(1))) uint32_t*)g,
      (__attribute__((address_space(3))) uint32_t*)l, 16, 0, 0);
}

// ---------------- fp32 -> bf16 conversion of all inputs ----------------
__global__ __launch_bounds__(256) void convert_kernel(
    const float* __restrict__ x,  const float* __restrict__ wq,
    const float* __restrict__ wk, const float* __restrict__ wv,
    const float* __restrict__ wo,
    u16* __restrict__ xb, u16* __restrict__ wqkvb, u16* __restrict__ wob) {
  const int64_t M1 = 1024 * 1024;
  int64_t e = ((int64_t)blockIdx.x * 256 + threadIdx.x) * 4;   // 0 .. 6M
  const float* src; u16* dst; int64_t off;
  if (e < 2 * M1)      { src = x;  dst = xb;           off = e; }
  else if (e < 3 * M1) { src = wq; dst = wqkvb;        off = e - 2 * M1; }
  else if (e < 4 * M1) { src = wk; dst = wqkvb + M1;   off = e - 3 * M1; }
  else if (e < 5 * M1) { src = wv; dst = wqkvb + 2*M1; off = e - 4 * M1; }
  else                 { src = wo; dst = wob;          off = e - 5 * M1; }
  float4 v = *(const float4*)(src + off);
  u16x4 o;
  o[0] = f2bf(v.x); o[1] = f2bf(v.y); o[2] = f2bf(v.z); o[3] = f2bf(v.w);
  *(u16x4*)(dst + off) = o;
}

// ---------------- GEMM (m97 128x128 structure): C = A[M,K] * B[N,K]^T ---
// EPI 0: QKV -> scatter Q[H][S][D], K[H][S][D], V^T[H][D][S] (bf16)
// EPI 1: out-proj -> fp32 C row-major [M][N]
template <int EPI>
__global__ __launch_bounds__(256, 2) void gemm_kernel(
    const u16* __restrict__ A, const u16* __restrict__ B, int K, int N,
    u16* __restrict__ q_ws, u16* __restrict__ k_ws, u16* __restrict__ vt_ws,
    float* __restrict__ Cout) {
  constexpr int BM = 128, BN = 128, BK = 32;
  __shared__ __align__(16) u16 As[BM * BK];
  __shared__ __align__(16) u16 Bs[BN * BK];
  const int t = threadIdx.x;
  const int lane = t & 63, w = t >> 6;
  const int wr = w >> 1, wc = w & 1;          // 2x2 waves, each 64x64
  const int fr = lane & 15, fg = lane >> 4;
  const int m0 = blockIdx.y * BM, n0 = blockIdx.x * BN;

  f32x4 acc[4][4] = {};

  for (int k0 = 0; k0 < K; k0 += BK) {
#pragma unroll
    for (int it = 0; it < 2; ++it) {           // A,B: 512 chunks each
      const int c = t + it * 256;
      gload_lds16(A + (int64_t)(m0 + (c >> 2)) * K + k0 + (c & 3) * 8,
                  As + (c & ~63) * 8);
      gload_lds16(B + (int64_t)(n0 + (c >> 2)) * K + k0 + (c & 3) * 8,
                  Bs + (c & ~63) * 8);
    }
    __syncthreads();
    bf16x8 af[4], bfr[4];
#pragma unroll
    for (int i = 0; i < 4; ++i) {
      af[i]  = __builtin_bit_cast(
          bf16x8, *(const u16x8*)&As[(wr * 64 + i * 16 + fr) * BK + fg * 8]);
      bfr[i] = __builtin_bit_cast(
          bf16x8, *(const u16x8*)&Bs[(wc * 64 + i * 16 + fr) * BK + fg * 8]);
    }
#pragma unroll
    for (int mi = 0; mi < 4; ++mi)
#pragma unroll
      for (int ni = 0; ni < 4; ++ni)
        acc[mi][ni] = __builtin_amdgcn_mfma_f32_16x16x32_bf16(
            af[mi], bfr[ni], acc[mi][ni], 0, 0, 0);
    __syncthreads();
  }

#pragma unroll
  for (int mi = 0; mi < 4; ++mi)
#pragma unroll
    for (int ni = 0; ni < 4; ++ni)
#pragma unroll
      for (int r = 0; r < 4; ++r) {
        const int m = m0 + wr * 64 + mi * 16 + fg * 4 + r;
        const int n = n0 + wc * 64 + ni * 16 + fr;
        const float v = acc[mi][ni][r];
        if constexpr (EPI == 0) {
          const int which = n >> 10, nn = n & 1023, h = nn >> 6, d = nn & 63;
          const u16 bv = f2bf(v);
          if (which == 0)      q_ws[((int64_t)h * SS + m) * DD + d] = bv;
          else if (which == 1) k_ws[((int64_t)h * SS + m) * DD + d] = bv;
          else                 vt_ws[((int64_t)h * DD + d) * SS + m] = bv;
        } else {
          Cout[(int64_t)m * N + n] = v;
        }
      }
}

// ---------------- flash attention: swapped QK^T, in-register softmax ----
// block = 4 waves, each wave owns 16 q-rows (64 q/block); grid (32, 16)
__global__ __launch_bounds__(256, 2) void attn_kernel(
    const u16* __restrict__ q_ws, const u16* __restrict__ k_ws,
    const u16* __restrict__ vt_ws, u16* __restrict__ a_ws) {
  constexpr int NT = SS / 64;                  // 32 key tiles
  // XOR-swizzled tiles: elem (row, d-chunk ch) at row*64 + (ch ^ (row&7))*8
  __shared__ __align__(16) u16 Ks[2][64 * 64]; // K tile  [key][d]
  __shared__ __align__(16) u16 Vs[2][64 * 64]; // V^T tile [dv][key]
  const int t = threadIdx.x;
  const int lane = t & 63, w = t >> 6;
  const int ql = lane & 15, g = lane >> 4;     // q-col / k-group of this lane
  const int h = blockIdx.y, qb = blockIdx.x;
  const int qbase = qb * 64 + w * 16;

  const u16* Qh = q_ws + ((int64_t)h * SS + qbase) * DD;
  const u16* Kh = k_ws + (int64_t)h * SS * DD;
  const u16* Vh = vt_ws + (int64_t)h * DD * SS;

  // staging chunk coords: 2 chunks each of K and V per thread
  const int c0 = t, c1 = t + 256;
  const int r0 = c0 >> 3, ch0 = c0 & 7, r1 = c1 >> 3, ch1 = c1 & 7;
  const int d0 = r0 * 64 + ((ch0 ^ (r0 & 7)) * 8);
  const int d1 = r1 * 64 + ((ch1 ^ (r1 & 7)) * 8);

  // Q B-fragments (col=q, k=d), direct from global, hoisted
  bf16x8 qf[2];
#pragma unroll
  for (int dd = 0; dd < 2; ++dd)
    qf[dd] = __builtin_bit_cast(
        bf16x8, *(const u16x8*)(Qh + ql * DD + dd * 32 + g * 8));

  f32x4 o[4] = {};                             // O[q=g*4+r][dv=nb*16+ql]
  float m_run = -1e30f, l_run = 0.f;
  const float C2 = 0.18033688f;                // 0.125 * log2(e)

  u16x8 gk0, gk1, gv0, gv1;
  gk0 = *(const u16x8*)(Kh + (int64_t)r0 * DD + ch0 * 8);
  gk1 = *(const u16x8*)(Kh + (int64_t)r1 * DD + ch1 * 8);
  gv0 = *(const u16x8*)(Vh + (int64_t)r0 * SS + ch0 * 8);
  gv1 = *(const u16x8*)(Vh + (int64_t)r1 * SS + ch1 * 8);
  *(u16x8*)&Ks[0][d0] = gk0; *(u16x8*)&Ks[0][d1] = gk1;
  *(u16x8*)&Vs[0][d0] = gv0; *(u16x8*)&Vs[0][d1] = gv1;
  __syncthreads();

  for (int kt = 0; kt < NT; ++kt) {
    const int cur = kt & 1;
    if (kt + 1 < NT) {                         // T14: issue next-tile loads now
      const u16* Kn = Kh + (int64_t)(kt + 1) * 64 * DD;
      const u16* Vn = Vh + (kt + 1) * 64;
      gk0 = *(const u16x8*)(Kn + (int64_t)r0 * DD + ch0 * 8);
      gk1 = *(const u16x8*)(Kn + (int64_t)r1 * DD + ch1 * 8);
      gv0 = *(const u16x8*)(Vn + (int64_t)r0 * SS + ch0 * 8);
      gv1 = *(const u16x8*)(Vn + (int64_t)r1 * SS + ch1 * 8);
    }

    // S^T = K Q^T : s[kb][r] = S[key=kb*16+g*4+r][q=ql]
    f32x4 s[4] = {};
#pragma unroll
    for (int dd = 0; dd < 2; ++dd)
#pragma unroll
      for (int kb = 0; kb < 4; ++kb) {
        const int key = kb * 16 + ql;
        bf16x8 kf = __builtin_bit_cast(
            bf16x8,
            *(const u16x8*)&Ks[cur][key * 64 + (((dd * 4 + g) ^ (key & 7)) * 8)]);
        s[kb] = __builtin_amdgcn_mfma_f32_16x16x32_bf16(kf, qf[dd], s[kb], 0, 0, 0);
      }

    // online softmax, in-register (lane group of 4 shares q=ql)
    float mx = s[0][0];
#pragma unroll
    for (int kb = 0; kb < 4; ++kb)
#pragma unroll
      for (int r = 0; r < 4; ++r) mx = fmaxf(mx, s[kb][r]);
    mx = fmaxf(mx, __shfl_xor(mx, 16));
    mx = fmaxf(mx, __shfl_xor(mx, 32));
    const float ts = mx * C2;
    const bool skip = __all(ts <= m_run + 8.0f);   // defer-max (T13)
    float sf = 1.f;
    if (!skip) {
      const float mnew = fmaxf(m_run, ts);
      sf = exp2f(m_run - mnew);
      m_run = mnew;
    }
    float p[4][4];
    float ls = 0.f;
#pragma unroll
    for (int kb = 0; kb < 4; ++kb)
#pragma unroll
      for (int r = 0; r < 4; ++r) {
        const float pv = exp2f(__fmaf_rn(s[kb][r], C2, -m_run));
        p[kb][r] = pv;
        ls += pv;
      }
    ls += __shfl_xor(ls, 16);
    ls += __shfl_xor(ls, 32);
    if (!skip) {
      l_run = __fmaf_rn(l_run, sf, ls);
#pragma unroll
      for (int r = 0; r < 4; ++r) {
        const float sfr = __shfl(sf, g * 4 + r);
#pragma unroll
        for (int nb = 0; nb < 4; ++nb) o[nb][r] *= sfr;
      }
    } else {
      l_run += ls;
    }

    // PV: rebuild A-frag (P[q][key]) in-register via cvt_pk + permlane swaps
#pragma unroll
    for (int ks = 0; ks < 2; ++ks) {
      u32 x0 = cvtpk(p[2 * ks][0], p[2 * ks][1]);
      u32 x1 = cvtpk(p[2 * ks][2], p[2 * ks][3]);
      u32 y0 = cvtpk(p[2 * ks + 1][0], p[2 * ks + 1][1]);
      u32 y1 = cvtpk(p[2 * ks + 1][2], p[2 * ks + 1][3]);
      asm("v_permlane32_swap_b32 %0, %1" : "+v"(x0), "+v"(y0));
      asm("v_permlane16_swap_b32 %0, %1" : "+v"(x0), "+v"(y0));
      asm("v_permlane32_swap_b32 %0, %1" : "+v"(x1), "+v"(y1));
      asm("v_permlane16_swap_b32 %0, %1" : "+v"(x1), "+v"(y1));
      u32x4 aw; aw[0] = x0; aw[1] = x1; aw[2] = y0; aw[3] = y1;
      const bf16x8 pa = __builtin_bit_cast(bf16x8, aw);
#pragma unroll
      for (int nb = 0; nb < 4; ++nb) {
        const int dv = nb * 16 + ql;
        bf16x8 vf = __builtin_bit_cast(
            bf16x8,
            *(const u16x8*)&Vs[cur][dv * 64 + (((ks * 4 + g) ^ (dv & 7)) * 8)]);
        o[nb] = __builtin_amdgcn_mfma_f32_16x16x32_bf16(pa, vf, o[nb], 0, 0, 0);
      }
    }

    __syncthreads();                            // all waves done reading buf[cur]
    if (kt + 1 < NT) {                          // write prefetched tile
      u16* Kd = (u16*)&Ks[cur ^ 1][0];
      u16* Vd = (u16*)&Vs[cur ^ 1][0];
      *(u16x8*)&Kd[d0] = gk0; *(u16x8*)&Kd[d1] = gk1;
      *(u16x8*)&Vd[d0] = gv0; *(u16x8*)&Vd[d1] = gv1;
    }
    __syncthreads();
  }

  // epilogue: normalize and store A[q][h*64+dv]
  const float linv = 1.0f / l_run;
#pragma unroll
  for (int r = 0; r < 4; ++r) {
    const float lr = __shfl(linv, g * 4 + r);
    const int q = qbase + g * 4 + r;
#pragma unroll
    for (int nb = 0; nb < 4; ++nb)
      a_ws[(int64_t)q * (HH * DD) + h * DD + nb * 16 + ql] = f2bf(o[nb][r] * lr);
  }
}

extern "C" void kernel_launch(void* const* d_in, const int* in_sizes, int n_in,
                              void* d_out, int out_size, void* d_ws, size_t ws_size,
                              hipStream_t stream) {
  const float* x  = (const float*)d_in[0];
  const float* wq = (const float*)d_in[1];
  const float* wk = (const float*)d_in[2];
  const float* wv = (const float*)d_in[3];
  const float* wo = (const float*)d_in[4];
  char* ws = (char*)d_ws;
  const int64_t Mi = 1 << 20;
  u16* xb   = (u16*)(ws + 0 * Mi);    // 4 MiB  (2M bf16)
  u16* wqkv = (u16*)(ws + 4 * Mi);    // 6 MiB  (3M bf16: Wq|Wk|Wv)
  u16* wob  = (u16*)(ws + 10 * Mi);   // 2 MiB
  u16* q_ws = (u16*)(ws + 12 * Mi);   // 4 MiB  [H][S][D]
  u16* k_ws = (u16*)(ws + 16 * Mi);   // 4 MiB  [H][S][D]
  u16* vt   = (u16*)(ws + 20 * Mi);   // 4 MiB  [H][D][S]
  u16* a_ws = (u16*)(ws + 24 * Mi);   // 4 MiB  [S][H*D]
  float* out = (float*)d_out;

  convert_kernel<<<6144, 256, 0, stream>>>(x, wq, wk, wv, wo, xb, wqkv, wob);

  // QKV: [2048,1024] x [3072,1024]^T
  gemm_kernel<0><<<dim3(3072 / 128, 2048 / 128), 256, 0, stream>>>(
      xb, wqkv, 1024, 3072, q_ws, k_ws, vt, nullptr);

  attn_kernel<<<dim3(SS / 64, HH), 256, 0, stream>>>(q_ws, k_ws, vt, a_ws);

  // out-proj: [2048,1024] x [1024,1024]^T -> fp32
  gemm_kernel<1><<<dim3(1024 / 128, 2048 / 128), 256, 0, stream>>>(
      a_ws, wob, 1024, 1024, nullptr, nullptr, nullptr, out);
}

// Round 3
// 94.926 us; speedup vs baseline: 1.3505x; 1.1848x over previous
//
#include <hip/hip_runtime.h>
#include <hip/hip_bf16.h>
#include <stdint.h>

typedef uint16_t u16;
typedef uint32_t u32;
typedef float    f32x4  __attribute__((ext_vector_type(4)));
typedef __bf16   bf16x8 __attribute__((ext_vector_type(8)));
typedef uint16_t u16x8  __attribute__((ext_vector_type(8)));
typedef uint16_t u16x4  __attribute__((ext_vector_type(4)));
typedef uint32_t u32x4  __attribute__((ext_vector_type(4)));

#define HH 16
#define SS 2048
#define EE 1024
#define DD 64

__device__ inline u16 f2bf(float f) {
  uint32_t u = __builtin_bit_cast(uint32_t, f);
  u += 0x7fff + ((u >> 16) & 1);   // RNE
  return (u16)(u >> 16);
}
__device__ inline float bf2f(u16 b) {
  return __builtin_bit_cast(float, (uint32_t)b << 16);
}

__device__ inline u32 cvtpk(float lo, float hi) {   // [15:0]=bf16(lo), [31:16]=bf16(hi)
  u32 r;
  asm("v_cvt_pk_bf16_f32 %0, %1, %2" : "=v"(r) : "v"(lo), "v"(hi));
  return r;
}

__device__ inline void gload_lds16(const void* g, void* l) {
  __builtin_amdgcn_global_load_lds(
      (const __attribute__((address_space(1))) uint32_t*)g,
      (__attribute__((address_space(3))) uint32_t*)l, 16, 0, 0);
}

// ---------------- fp32 -> bf16 conversion of all inputs ----------------
__global__ __launch_bounds__(256) void convert_kernel(
    const float* __restrict__ x,  const float* __restrict__ wq,
    const float* __restrict__ wk, const float* __restrict__ wv,
    const float* __restrict__ wo,
    u16* __restrict__ xb, u16* __restrict__ wqkvb, u16* __restrict__ wob) {
  const int64_t M1 = 1024 * 1024;
  int64_t e = ((int64_t)blockIdx.x * 256 + threadIdx.x) * 4;   // 0 .. 6M
  const float* src; u16* dst; int64_t off;
  if (e < 2 * M1)      { src = x;  dst = xb;           off = e; }
  else if (e < 3 * M1) { src = wq; dst = wqkvb;        off = e - 2 * M1; }
  else if (e < 4 * M1) { src = wk; dst = wqkvb + M1;   off = e - 3 * M1; }
  else if (e < 5 * M1) { src = wv; dst = wqkvb + 2*M1; off = e - 4 * M1; }
  else                 { src = wo; dst = wob;          off = e - 5 * M1; }
  float4 v = *(const float4*)(src + off);
  u16x4 o;
  o[0] = f2bf(v.x); o[1] = f2bf(v.y); o[2] = f2bf(v.z); o[3] = f2bf(v.w);
  *(u16x4*)(dst + off) = o;
}

// ---------------- GEMM: C[M,N] = A[M,K] * B[N,K]^T, BK=64, T2 swizzle ---
// LDS tile rows are 8x16B chunks; global chunk ch is loaded into slot
// ch^(row&7) via pre-swizzled SOURCE address (linear gload_lds dest),
// fragment reads apply the same XOR -> conflict-free ds_read_b128.
// EPI 0: QKV -> scatter Q[H][S][D], K[H][S][D], V^T[H][D][S] (bf16)
// EPI 1: out-proj -> fp32 C row-major [M][N]
template <int EPI>
__global__ __launch_bounds__(256, 4) void gemm_kernel(
    const u16* __restrict__ A, const u16* __restrict__ B, int K, int N,
    u16* __restrict__ q_ws, u16* __restrict__ k_ws, u16* __restrict__ vt_ws,
    float* __restrict__ Cout) {
  constexpr int BM = 64, BN = 128, BK = 64;
  __shared__ __align__(16) u16 As[BM * BK];
  __shared__ __align__(16) u16 Bs[BN * BK];
  const int t = threadIdx.x;
  const int lane = t & 63, w = t >> 6;
  const int wr = w >> 1, wc = w & 1;          // 2x2 waves, each 32x64
  const int fr = lane & 15, fg = lane >> 4;

  // bijective XCD swizzle (nwg % 8 == 0 for both launches)
  const int nwg = gridDim.x * gridDim.y;
  const int bid = blockIdx.y * gridDim.x + blockIdx.x;
  const int swz = (bid & 7) * (nwg >> 3) + (bid >> 3);
  const int m0 = (swz / gridDim.x) * BM, n0 = (swz % gridDim.x) * BN;

  f32x4 acc[2][4] = {};

  for (int k0 = 0; k0 < K; k0 += BK) {
#pragma unroll
    for (int it = 0; it < 2; ++it) {           // A: 512 chunks
      const int c = t + it * 256, row = c >> 3, sch = (c & 7) ^ (row & 7);
      gload_lds16(A + (int64_t)(m0 + row) * K + k0 + sch * 8,
                  As + (c & ~63) * 8);
    }
#pragma unroll
    for (int it = 0; it < 4; ++it) {           // B: 1024 chunks
      const int c = t + it * 256, row = c >> 3, sch = (c & 7) ^ (row & 7);
      gload_lds16(B + (int64_t)(n0 + row) * K + k0 + sch * 8,
                  Bs + (c & ~63) * 8);
    }
    __syncthreads();
    bf16x8 af[2][2], bfr[4][2];
#pragma unroll
    for (int mi = 0; mi < 2; ++mi)
#pragma unroll
      for (int kc = 0; kc < 2; ++kc) {
        const int row = wr * 32 + mi * 16 + fr;
        const int cc = (kc * 4 + fg) ^ (row & 7);
        af[mi][kc] = __builtin_bit_cast(bf16x8, *(const u16x8*)&As[row * 64 + cc * 8]);
      }
#pragma unroll
    for (int ni = 0; ni < 4; ++ni)
#pragma unroll
      for (int kc = 0; kc < 2; ++kc) {
        const int row = wc * 64 + ni * 16 + fr;
        const int cc = (kc * 4 + fg) ^ (row & 7);
        bfr[ni][kc] = __builtin_bit_cast(bf16x8, *(const u16x8*)&Bs[row * 64 + cc * 8]);
      }
#pragma unroll
    for (int kc = 0; kc < 2; ++kc)
#pragma unroll
      for (int mi = 0; mi < 2; ++mi)
#pragma unroll
        for (int ni = 0; ni < 4; ++ni)
          acc[mi][ni] = __builtin_amdgcn_mfma_f32_16x16x32_bf16(
              af[mi][kc], bfr[ni][kc], acc[mi][ni], 0, 0, 0);
    __syncthreads();
  }

#pragma unroll
  for (int mi = 0; mi < 2; ++mi)
#pragma unroll
    for (int ni = 0; ni < 4; ++ni)
#pragma unroll
      for (int r = 0; r < 4; ++r) {
        const int m = m0 + wr * 32 + mi * 16 + fg * 4 + r;
        const int n = n0 + wc * 64 + ni * 16 + fr;
        const float v = acc[mi][ni][r];
        if constexpr (EPI == 0) {
          const int which = n >> 10, nn = n & 1023, h = nn >> 6, d = nn & 63;
          const u16 bv = f2bf(v);
          if (which == 0)      q_ws[((int64_t)h * SS + m) * DD + d] = bv;
          else if (which == 1) k_ws[((int64_t)h * SS + m) * DD + d] = bv;
          else                 vt_ws[((int64_t)h * DD + d) * SS + m] = bv;
        } else {
          Cout[(int64_t)m * N + n] = v;
        }
      }
}

// ---------------- flash attention, split-KV x2 --------------------------
// grid (32 qb, 16 h, 2 sp); block = 4 waves, each wave owns 16 q-rows.
// Writes unnormalized O partial (bf16) + (m,l) f32; combine_kernel merges.
__global__ __launch_bounds__(256, 4) void attn_kernel(
    const u16* __restrict__ q_ws, const u16* __restrict__ k_ws,
    const u16* __restrict__ vt_ws, u16* __restrict__ opart,
    float2* __restrict__ ml) {
  constexpr int NT2 = SS / 64 / 2;             // 16 key tiles per split
  __shared__ __align__(16) u16 Ks[2][64 * 64]; // K tile  [key][d], swizzled
  __shared__ __align__(16) u16 Vs[2][64 * 64]; // V^T tile [dv][key], swizzled
  const int t = threadIdx.x;
  const int lane = t & 63, w = t >> 6;
  const int ql = lane & 15, g = lane >> 4;
  const int h = blockIdx.y, qb = blockIdx.x, sp = blockIdx.z;
  const int kt0 = sp * NT2;
  const int qbase = qb * 64 + w * 16;

  const u16* Qh = q_ws + ((int64_t)h * SS + qbase) * DD;
  const u16* Kh = k_ws + (int64_t)h * SS * DD;
  const u16* Vh = vt_ws + (int64_t)h * DD * SS;

  const int c0 = t, c1 = t + 256;
  const int r0 = c0 >> 3, ch0 = c0 & 7, r1 = c1 >> 3, ch1 = c1 & 7;
  const int d0 = r0 * 64 + ((ch0 ^ (r0 & 7)) * 8);
  const int d1 = r1 * 64 + ((ch1 ^ (r1 & 7)) * 8);

  bf16x8 qf[2];
#pragma unroll
  for (int dd = 0; dd < 2; ++dd)
    qf[dd] = __builtin_bit_cast(
        bf16x8, *(const u16x8*)(Qh + ql * DD + dd * 32 + g * 8));

  f32x4 o[4] = {};                             // O[q=g*4+r][dv=nb*16+ql]
  float m_run = -1e30f, l_run = 0.f;
  const float C2 = 0.18033688f;                // 0.125 * log2(e)

  u16x8 gk0, gk1, gv0, gv1;
  gk0 = *(const u16x8*)(Kh + (int64_t)(kt0 * 64 + r0) * DD + ch0 * 8);
  gk1 = *(const u16x8*)(Kh + (int64_t)(kt0 * 64 + r1) * DD + ch1 * 8);
  gv0 = *(const u16x8*)(Vh + (int64_t)r0 * SS + kt0 * 64 + ch0 * 8);
  gv1 = *(const u16x8*)(Vh + (int64_t)r1 * SS + kt0 * 64 + ch1 * 8);
  *(u16x8*)&Ks[0][d0] = gk0; *(u16x8*)&Ks[0][d1] = gk1;
  *(u16x8*)&Vs[0][d0] = gv0; *(u16x8*)&Vs[0][d1] = gv1;
  __syncthreads();

  for (int kt = 0; kt < NT2; ++kt) {
    const int cur = kt & 1;
    if (kt + 1 < NT2) {                        // T14: issue next-tile loads now
      const int kg = kt0 + kt + 1;
      const u16* Kn = Kh + (int64_t)kg * 64 * DD;
      const u16* Vn = Vh + kg * 64;
      gk0 = *(const u16x8*)(Kn + (int64_t)r0 * DD + ch0 * 8);
      gk1 = *(const u16x8*)(Kn + (int64_t)r1 * DD + ch1 * 8);
      gv0 = *(const u16x8*)(Vn + (int64_t)r0 * SS + ch0 * 8);
      gv1 = *(const u16x8*)(Vn + (int64_t)r1 * SS + ch1 * 8);
    }

    // S^T = K Q^T : s[kb][r] = S[key=kb*16+g*4+r][q=ql]
    f32x4 s[4] = {};
    __builtin_amdgcn_s_setprio(1);
#pragma unroll
    for (int dd = 0; dd < 2; ++dd)
#pragma unroll
      for (int kb = 0; kb < 4; ++kb) {
        const int key = kb * 16 + ql;
        bf16x8 kf = __builtin_bit_cast(
            bf16x8,
            *(const u16x8*)&Ks[cur][key * 64 + (((dd * 4 + g) ^ (key & 7)) * 8)]);
        s[kb] = __builtin_amdgcn_mfma_f32_16x16x32_bf16(kf, qf[dd], s[kb], 0, 0, 0);
      }
    __builtin_amdgcn_s_setprio(0);

    // online softmax, in-register
    float mx = s[0][0];
#pragma unroll
    for (int kb = 0; kb < 4; ++kb)
#pragma unroll
      for (int r = 0; r < 4; ++r) mx = fmaxf(mx, s[kb][r]);
    mx = fmaxf(mx, __shfl_xor(mx, 16));
    mx = fmaxf(mx, __shfl_xor(mx, 32));
    const float ts = mx * C2;
    const bool skip = __all(ts <= m_run + 8.0f);   // defer-max (T13)
    float sf = 1.f;
    if (!skip) {
      const float mnew = fmaxf(m_run, ts);
      sf = exp2f(m_run - mnew);
      m_run = mnew;
    }
    float p[4][4];
    float ls = 0.f;
#pragma unroll
    for (int kb = 0; kb < 4; ++kb)
#pragma unroll
      for (int r = 0; r < 4; ++r) {
        const float pv = exp2f(__fmaf_rn(s[kb][r], C2, -m_run));
        p[kb][r] = pv;
        ls += pv;
      }
    ls += __shfl_xor(ls, 16);
    ls += __shfl_xor(ls, 32);
    if (!skip) {
      l_run = __fmaf_rn(l_run, sf, ls);
#pragma unroll
      for (int r = 0; r < 4; ++r) {
        const float sfr = __shfl(sf, g * 4 + r);
#pragma unroll
        for (int nb = 0; nb < 4; ++nb) o[nb][r] *= sfr;
      }
    } else {
      l_run += ls;
    }

    // PV: rebuild A-frag (P[q][key]) in-register via cvt_pk + permlane swaps
#pragma unroll
    for (int ks = 0; ks < 2; ++ks) {
      u32 x0 = cvtpk(p[2 * ks][0], p[2 * ks][1]);
      u32 x1 = cvtpk(p[2 * ks][2], p[2 * ks][3]);
      u32 y0 = cvtpk(p[2 * ks + 1][0], p[2 * ks + 1][1]);
      u32 y1 = cvtpk(p[2 * ks + 1][2], p[2 * ks + 1][3]);
      asm("v_permlane32_swap_b32 %0, %1" : "+v"(x0), "+v"(y0));
      asm("v_permlane16_swap_b32 %0, %1" : "+v"(x0), "+v"(y0));
      asm("v_permlane32_swap_b32 %0, %1" : "+v"(x1), "+v"(y1));
      asm("v_permlane16_swap_b32 %0, %1" : "+v"(x1), "+v"(y1));
      u32x4 aw; aw[0] = x0; aw[1] = x1; aw[2] = y0; aw[3] = y1;
      const bf16x8 pa = __builtin_bit_cast(bf16x8, aw);
      __builtin_amdgcn_s_setprio(1);
#pragma unroll
      for (int nb = 0; nb < 4; ++nb) {
        const int dv = nb * 16 + ql;
        bf16x8 vf = __builtin_bit_cast(
            bf16x8,
            *(const u16x8*)&Vs[cur][dv * 64 + (((ks * 4 + g) ^ (dv & 7)) * 8)]);
        o[nb] = __builtin_amdgcn_mfma_f32_16x16x32_bf16(pa, vf, o[nb], 0, 0, 0);
      }
      __builtin_amdgcn_s_setprio(0);
    }

    __syncthreads();                            // all waves done reading buf[cur]
    if (kt + 1 < NT2) {                         // write prefetched tile
      u16* Kd = (u16*)&Ks[cur ^ 1][0];
      u16* Vd = (u16*)&Vs[cur ^ 1][0];
      *(u16x8*)&Kd[d0] = gk0; *(u16x8*)&Kd[d1] = gk1;
      *(u16x8*)&Vd[d0] = gv0; *(u16x8*)&Vd[d1] = gv1;
    }
    __syncthreads();
  }

  // epilogue: store unnormalized O partial (bf16) + per-q (m,l)
  const int64_t rowbase = ((int64_t)sp * HH + h) * SS;
#pragma unroll
  for (int r = 0; r < 4; ++r) {
    const int q = qbase + g * 4 + r;
#pragma unroll
    for (int nb = 0; nb < 4; ++nb)
      opart[(rowbase + q) * DD + nb * 16 + ql] = f2bf(o[nb][r]);
  }
  if (g == 0) ml[rowbase + qbase + ql] = make_float2(m_run, l_run);
}

// ---------------- combine two KV-splits -> a_ws bf16 [S][H*DV] ----------
__global__ __launch_bounds__(256) void combine_kernel(
    const u16* __restrict__ opart, const float2* __restrict__ ml,
    u16* __restrict__ a_ws) {
  const int rid = blockIdx.x * 4 + (threadIdx.x >> 6);   // 0 .. 16*2048-1
  const int lane = threadIdx.x & 63;
  const int h = rid >> 11, q = rid & 2047;
  const float2 ml1 = ml[rid];
  const float2 ml2 = ml[HH * SS + rid];
  const float m = fmaxf(ml1.x, ml2.x);
  const float a1 = exp2f(ml1.x - m), a2 = exp2f(ml2.x - m);
  const float inv = 1.0f / __fmaf_rn(a1, ml1.y, a2 * ml2.y);
  const float o1 = bf2f(opart[(int64_t)rid * DD + lane]);
  const float o2 = bf2f(opart[((int64_t)HH * SS + rid) * DD + lane]);
  a_ws[(int64_t)q * (HH * DD) + h * DD + lane] =
      f2bf((a1 * o1 + a2 * o2) * inv);
}

extern "C" void kernel_launch(void* const* d_in, const int* in_sizes, int n_in,
                              void* d_out, int out_size, void* d_ws, size_t ws_size,
                              hipStream_t stream) {
  const float* x  = (const float*)d_in[0];
  const float* wq = (const float*)d_in[1];
  const float* wk = (const float*)d_in[2];
  const float* wv = (const float*)d_in[3];
  const float* wo = (const float*)d_in[4];
  char* ws = (char*)d_ws;
  const int64_t Mi = 1 << 20;
  // phase 1 (convert + QKV GEMM):
  u16* xb    = (u16*)(ws + 0 * Mi);    // 0-4 MiB   (dead after QKV GEMM)
  u16* wqkv  = (u16*)(ws + 4 * Mi);    // 4-10 MiB  (dead after QKV GEMM)
  u16* q_ws  = (u16*)(ws + 12 * Mi);   // 12-16 MiB (dead after attn)
  u16* k_ws  = (u16*)(ws + 16 * Mi);   // 16-20 MiB (dead after attn)
  u16* vt    = (u16*)(ws + 20 * Mi);   // 20-24 MiB (dead after attn)
  u16* wob   = (u16*)(ws + 24 * Mi);   // 24-26 MiB (live until out-proj)
  // phase 2 (attn partials, over the dead 0-10 MiB zone):
  u16*    opart = (u16*)(ws + 0 * Mi);     // 0-8 MiB  [2][16][2048][64] bf16
  float2* mlv   = (float2*)(ws + 8 * Mi);  // 8-8.5 MiB [2][16][2048] (m,l)
  // phase 3 (combine out, over dead q_ws):
  u16* a_ws  = (u16*)(ws + 12 * Mi);   // 12-16 MiB [S][H*DV]
  float* out = (float*)d_out;

  convert_kernel<<<6144, 256, 0, stream>>>(x, wq, wk, wv, wo, xb, wqkv, wob);

  // QKV: [2048,1024] x [3072,1024]^T  (grid 24x32 = 768 blocks)
  gemm_kernel<0><<<dim3(3072 / 128, 2048 / 64), 256, 0, stream>>>(
      xb, wqkv, 1024, 3072, q_ws, k_ws, vt, nullptr);

  attn_kernel<<<dim3(SS / 64, HH, 2), 256, 0, stream>>>(q_ws, k_ws, vt, opart, mlv);

  combine_kernel<<<HH * SS / 4, 256, 0, stream>>>(opart, mlv, a_ws);

  // out-proj: [2048,1024] x [1024,1024]^T -> fp32  (grid 8x32 = 256 blocks)
  gemm_kernel<1><<<dim3(1024 / 128, 2048 / 64), 256, 0, stream>>>(
      a_ws, wob, 1024, 1024, nullptr, nullptr, nullptr, out);
}

// Round 4
// 92.738 us; speedup vs baseline: 1.3824x; 1.0236x over previous
//
#include <hip/hip_runtime.h>
#include <hip/hip_bf16.h>
#include <stdint.h>

typedef uint16_t u16;
typedef uint32_t u32;
typedef float    f32x4  __attribute__((ext_vector_type(4)));
typedef __bf16   bf16x8 __attribute__((ext_vector_type(8)));
typedef uint16_t u16x8  __attribute__((ext_vector_type(8)));
typedef uint16_t u16x4  __attribute__((ext_vector_type(4)));
typedef uint32_t u32x4  __attribute__((ext_vector_type(4)));

#define HH 16
#define SS 2048
#define EE 1024
#define DD 64

__device__ inline u16 f2bf(float f) {
  uint32_t u = __builtin_bit_cast(uint32_t, f);
  u += 0x7fff + ((u >> 16) & 1);   // RNE
  return (u16)(u >> 16);
}
__device__ inline float bf2f(u16 b) {
  return __builtin_bit_cast(float, (uint32_t)b << 16);
}

__device__ inline u32 cvtpk(float lo, float hi) {   // [15:0]=bf16(lo), [31:16]=bf16(hi)
  u32 r;
  asm("v_cvt_pk_bf16_f32 %0, %1, %2" : "=v"(r) : "v"(lo), "v"(hi));
  return r;
}

__device__ inline void gload_lds16(const void* g, void* l) {
  __builtin_amdgcn_global_load_lds(
      (const __attribute__((address_space(1))) uint32_t*)g,
      (__attribute__((address_space(3))) uint32_t*)l, 16, 0, 0);
}

// ---------------- fp32 -> bf16 conversion of all inputs ----------------
__global__ __launch_bounds__(256) void convert_kernel(
    const float* __restrict__ x,  const float* __restrict__ wq,
    const float* __restrict__ wk, const float* __restrict__ wv,
    const float* __restrict__ wo,
    u16* __restrict__ xb, u16* __restrict__ wqkvb, u16* __restrict__ wob) {
  const int64_t M1 = 1024 * 1024;
  int64_t e = ((int64_t)blockIdx.x * 256 + threadIdx.x) * 4;   // 0 .. 6M
  const float* src; u16* dst; int64_t off;
  if (e < 2 * M1)      { src = x;  dst = xb;           off = e; }
  else if (e < 3 * M1) { src = wq; dst = wqkvb;        off = e - 2 * M1; }
  else if (e < 4 * M1) { src = wk; dst = wqkvb + M1;   off = e - 3 * M1; }
  else if (e < 5 * M1) { src = wv; dst = wqkvb + 2*M1; off = e - 4 * M1; }
  else                 { src = wo; dst = wob;          off = e - 5 * M1; }
  float4 v = *(const float4*)(src + off);
  u16x4 o;
  o[0] = f2bf(v.x); o[1] = f2bf(v.y); o[2] = f2bf(v.z); o[3] = f2bf(v.w);
  *(u16x4*)(dst + off) = o;
}

// ---------------- GEMM: C[M,N] = A[M,K] * B[N,K]^T, BK=64, T2 swizzle ---
template <int EPI, int K, int N>
__global__ __launch_bounds__(256, 4) void gemm_kernel(
    const u16* __restrict__ A, const u16* __restrict__ B,
    u16* __restrict__ q_ws, u16* __restrict__ k_ws, u16* __restrict__ vt_ws,
    float* __restrict__ Cout) {
  constexpr int BM = 64, BN = 128, BK = 64;
  __shared__ __align__(16) u16 As[BM * BK];
  __shared__ __align__(16) u16 Bs[BN * BK];
  const int t = threadIdx.x;
  const int lane = t & 63, w = t >> 6;
  const int wr = w >> 1, wc = w & 1;          // 2x2 waves, each 32x64
  const int fr = lane & 15, fg = lane >> 4;

  // bijective XCD swizzle (nwg % 8 == 0 for both launches)
  const int nwg = gridDim.x * gridDim.y;
  const int bid = blockIdx.y * gridDim.x + blockIdx.x;
  const int swz = (bid & 7) * (nwg >> 3) + (bid >> 3);
  const int m0 = (swz / gridDim.x) * BM, n0 = (swz % gridDim.x) * BN;

  f32x4 acc[2][4] = {};

  for (int k0 = 0; k0 < K; k0 += BK) {
#pragma unroll
    for (int it = 0; it < 2; ++it) {           // A: 512 chunks
      const int c = t + it * 256, row = c >> 3, sch = (c & 7) ^ (row & 7);
      gload_lds16(A + (int64_t)(m0 + row) * K + k0 + sch * 8,
                  As + (c & ~63) * 8);
    }
#pragma unroll
    for (int it = 0; it < 4; ++it) {           // B: 1024 chunks
      const int c = t + it * 256, row = c >> 3, sch = (c & 7) ^ (row & 7);
      gload_lds16(B + (int64_t)(n0 + row) * K + k0 + sch * 8,
                  Bs + (c & ~63) * 8);
    }
    __syncthreads();
    bf16x8 af[2][2], bfr[4][2];
#pragma unroll
    for (int mi = 0; mi < 2; ++mi)
#pragma unroll
      for (int kc = 0; kc < 2; ++kc) {
        const int row = wr * 32 + mi * 16 + fr;
        const int cc = (kc * 4 + fg) ^ (row & 7);
        af[mi][kc] = __builtin_bit_cast(bf16x8, *(const u16x8*)&As[row * 64 + cc * 8]);
      }
#pragma unroll
    for (int ni = 0; ni < 4; ++ni)
#pragma unroll
      for (int kc = 0; kc < 2; ++kc) {
        const int row = wc * 64 + ni * 16 + fr;
        const int cc = (kc * 4 + fg) ^ (row & 7);
        bfr[ni][kc] = __builtin_bit_cast(bf16x8, *(const u16x8*)&Bs[row * 64 + cc * 8]);
      }
#pragma unroll
    for (int kc = 0; kc < 2; ++kc)
#pragma unroll
      for (int mi = 0; mi < 2; ++mi)
#pragma unroll
        for (int ni = 0; ni < 4; ++ni)
          acc[mi][ni] = __builtin_amdgcn_mfma_f32_16x16x32_bf16(
              af[mi][kc], bfr[ni][kc], acc[mi][ni], 0, 0, 0);
    __syncthreads();
  }

#pragma unroll
  for (int mi = 0; mi < 2; ++mi)
#pragma unroll
    for (int ni = 0; ni < 4; ++ni)
#pragma unroll
      for (int r = 0; r < 4; ++r) {
        const int m = m0 + wr * 32 + mi * 16 + fg * 4 + r;
        const int n = n0 + wc * 64 + ni * 16 + fr;
        const float v = acc[mi][ni][r];
        if constexpr (EPI == 0) {
          const int which = n >> 10, nn = n & 1023, h = nn >> 6, d = nn & 63;
          const u16 bv = f2bf(v);
          if (which == 0)      q_ws[((int64_t)h * SS + m) * DD + d] = bv;
          else if (which == 1) k_ws[((int64_t)h * SS + m) * DD + d] = bv;
          else                 vt_ws[((int64_t)h * DD + d) * SS + m] = bv;
        } else {
          Cout[(int64_t)m * N + n] = v;
        }
      }
}

// ---------------- flash attention, split-KV x2, software-pipelined ------
// grid (32 qb, 16 h, 2 sp); block = 4 waves, each wave owns 16 q-rows.
// iter t: [barrier] stage K(t+1),V(t) | QK^T(t)->s_cur | softmax+PV(t-1)
__global__ __launch_bounds__(256, 4) void attn_kernel(
    const u16* __restrict__ q_ws, const u16* __restrict__ k_ws,
    const u16* __restrict__ vt_ws, u16* __restrict__ opart,
    float2* __restrict__ ml) {
  constexpr int NT2 = SS / 64 / 2;             // 16 key tiles per split
  // 4 x 8KB buffers: Kb0 @0, Kb1 @4096, Vb0 @8192, Vb1 @12288 (u16 units)
  __shared__ __align__(16) u16 lds[16384];
  const int t = threadIdx.x;
  const int lane = t & 63, w = t >> 6;
  const int ql = lane & 15, g = lane >> 4;
  const int h = blockIdx.y, qb = blockIdx.x, sp = blockIdx.z;
  const int kt0 = sp * NT2;
  const int qbase = qb * 64 + w * 16;

  const u16* Qh = q_ws + ((int64_t)h * SS + qbase) * DD;
  const u16* Kh = k_ws + ((int64_t)h * SS + kt0 * 64) * DD;
  const u16* Vh = vt_ws + (int64_t)h * DD * SS + kt0 * 64;

  // staging: thread covers chunks c=t and c=t+256 (of 512 16B chunks/tile)
  const int r0 = t >> 3, ch = t & 7, r1 = (t + 256) >> 3;
  const int sch0 = ch ^ (r0 & 7), sch1 = ch ^ (r1 & 7);
  const int64_t ko0 = (int64_t)r0 * DD + sch0 * 8;
  const int64_t ko1 = (int64_t)r1 * DD + sch1 * 8;
  const int64_t vo0 = (int64_t)r0 * SS + sch0 * 8;
  const int64_t vo1 = (int64_t)r1 * SS + sch1 * 8;
  const int dst0 = (t & ~63) * 8, dst1 = (t & ~63) * 8 + 2048;

  bf16x8 qf[2];
#pragma unroll
  for (int dd = 0; dd < 2; ++dd)
    qf[dd] = __builtin_bit_cast(
        bf16x8, *(const u16x8*)(Qh + ql * DD + dd * 32 + g * 8));

  f32x4 o[4] = {};                             // O[q=g*4+r][dv=nb*16+ql]
  float m_run = -1e30f, l_run = 0.f;
  float sf = 1.f;
  const float C2 = 0.18033688f;                // 0.125 * log2(e)

  // QK^T(tile) from K buffer kb_ -> s (S^T: s[kb][r] = S[key=kb*16+g*4+r][q=ql])
  auto qk = [&](f32x4 (&s)[4], const int kb_) {
    __builtin_amdgcn_s_setprio(1);
#pragma unroll
    for (int kb = 0; kb < 4; ++kb) {
      const int key = kb * 16 + ql;
      f32x4 z = {};
#pragma unroll
      for (int dd = 0; dd < 2; ++dd) {
        bf16x8 kf = __builtin_bit_cast(
            bf16x8,
            *(const u16x8*)&lds[kb_ * 4096 + key * 64 +
                                (((dd * 4 + g) ^ (ql & 7)) * 8)]);
        z = __builtin_amdgcn_mfma_f32_16x16x32_bf16(kf, qf[dd], z, 0, 0, 0);
      }
      s[kb] = z;
    }
    __builtin_amdgcn_s_setprio(0);
  };

  // softmax(s) + PV from V buffer vb_ (in-place p over s)
  auto smpv = [&](f32x4 (&s)[4], const int vb_) {
    float m01 = fmaxf(fmaxf(s[0][0], s[0][1]), fmaxf(s[0][2], s[0][3]));
    float m23 = fmaxf(fmaxf(s[1][0], s[1][1]), fmaxf(s[1][2], s[1][3]));
    float m45 = fmaxf(fmaxf(s[2][0], s[2][1]), fmaxf(s[2][2], s[2][3]));
    float m67 = fmaxf(fmaxf(s[3][0], s[3][1]), fmaxf(s[3][2], s[3][3]));
    float mx = fmaxf(fmaxf(m01, m23), fmaxf(m45, m67));
    mx = fmaxf(mx, __shfl_xor(mx, 16));
    mx = fmaxf(mx, __shfl_xor(mx, 32));
    const float ts = mx * C2;
    const bool skip = __all(ts <= m_run + 8.0f);   // defer-max (T13)
    if (!skip) {
      const float mnew = fmaxf(m_run, ts);
      sf = exp2f(m_run - mnew);
      m_run = mnew;
    }
    float ls = 0.f;
#pragma unroll
    for (int kb = 0; kb < 4; ++kb)
#pragma unroll
      for (int r = 0; r < 4; ++r) {
        const float pv = exp2f(__fmaf_rn(s[kb][r], C2, -m_run));
        s[kb][r] = pv;
        ls += pv;
      }
    ls += __shfl_xor(ls, 16);
    ls += __shfl_xor(ls, 32);
    if (!skip) {
      l_run = __fmaf_rn(l_run, sf, ls);
#pragma unroll
      for (int r = 0; r < 4; ++r) {
        const float sfr = __shfl(sf, g * 4 + r);
#pragma unroll
        for (int nb = 0; nb < 4; ++nb) o[nb][r] *= sfr;
      }
    } else {
      l_run += ls;
    }
    // rebuild PV A-frag in-register via cvt_pk + permlane swaps
#pragma unroll
    for (int ks = 0; ks < 2; ++ks) {
      u32 x0 = cvtpk(s[2 * ks][0], s[2 * ks][1]);
      u32 x1 = cvtpk(s[2 * ks][2], s[2 * ks][3]);
      u32 y0 = cvtpk(s[2 * ks + 1][0], s[2 * ks + 1][1]);
      u32 y1 = cvtpk(s[2 * ks + 1][2], s[2 * ks + 1][3]);
      asm("v_permlane32_swap_b32 %0, %1" : "+v"(x0), "+v"(y0));
      asm("v_permlane16_swap_b32 %0, %1" : "+v"(x0), "+v"(y0));
      asm("v_permlane32_swap_b32 %0, %1" : "+v"(x1), "+v"(y1));
      asm("v_permlane16_swap_b32 %0, %1" : "+v"(x1), "+v"(y1));
      u32x4 aw; aw[0] = x0; aw[1] = x1; aw[2] = y0; aw[3] = y1;
      const bf16x8 pa = __builtin_bit_cast(bf16x8, aw);
      __builtin_amdgcn_s_setprio(1);
#pragma unroll
      for (int nb = 0; nb < 4; ++nb) {
        const int dv = nb * 16 + ql;
        bf16x8 vf = __builtin_bit_cast(
            bf16x8,
            *(const u16x8*)&lds[8192 + vb_ * 4096 + dv * 64 +
                                (((ks * 4 + g) ^ (ql & 7)) * 8)]);
        o[nb] = __builtin_amdgcn_mfma_f32_16x16x32_bf16(pa, vf, o[nb], 0, 0, 0);
      }
      __builtin_amdgcn_s_setprio(0);
    }
  };

  // prologue: K(0) -> Kb[0]
  gload_lds16(Kh + ko0, lds + dst0);
  gload_lds16(Kh + ko1, lds + dst1);

  f32x4 sA[4], sB[4];
#pragma unroll
  for (int tt = 0; tt < NT2; ++tt) {
    __syncthreads();                           // drains vmcnt of prev stage
    if (tt + 1 < NT2) {                        // stage K(tt+1) -> Kb[(tt+1)&1]
      const u16* Kn = Kh + (int64_t)(tt + 1) * 64 * DD;
      const int kb = ((tt + 1) & 1) * 4096;
      gload_lds16(Kn + ko0, lds + kb + dst0);
      gload_lds16(Kn + ko1, lds + kb + dst1);
    }
    {                                          // stage V(tt) -> Vb[tt&1]
      const u16* Vn = Vh + tt * 64;
      const int vb = 8192 + (tt & 1) * 4096;
      gload_lds16(Vn + vo0, lds + vb + dst0);
      gload_lds16(Vn + vo1, lds + vb + dst1);
    }
    if (tt & 1) {
      qk(sB, tt & 1);
      smpv(sA, (tt - 1) & 1);                  // finish previous tile
    } else {
      qk(sA, tt & 1);
      if (tt > 0) smpv(sB, (tt - 1) & 1);
    }
  }
  __syncthreads();                             // V(NT2-1) visible
  smpv(sB, (NT2 - 1) & 1);                     // tail (NT2 even -> last in sB)

  // epilogue: store unnormalized O partial (bf16) + per-q (m,l)
  const int64_t rowbase = ((int64_t)sp * HH + h) * SS;
#pragma unroll
  for (int r = 0; r < 4; ++r) {
    const int q = qbase + g * 4 + r;
#pragma unroll
    for (int nb = 0; nb < 4; ++nb)
      opart[(rowbase + q) * DD + nb * 16 + ql] = f2bf(o[nb][r]);
  }
  if (g == 0) ml[rowbase + qbase + ql] = make_float2(m_run, l_run);
}

// ---------------- combine two KV-splits -> a_ws bf16 [S][H*DV] ----------
__global__ __launch_bounds__(256) void combine_kernel(
    const u16* __restrict__ opart, const float2* __restrict__ ml,
    u16* __restrict__ a_ws) {
  const int rid = blockIdx.x * 4 + (threadIdx.x >> 6);   // 0 .. 16*2048-1
  const int lane = threadIdx.x & 63;
  const int h = rid >> 11, q = rid & 2047;
  const float2 ml1 = ml[rid];
  const float2 ml2 = ml[HH * SS + rid];
  const float m = fmaxf(ml1.x, ml2.x);
  const float a1 = exp2f(ml1.x - m), a2 = exp2f(ml2.x - m);
  const float inv = 1.0f / __fmaf_rn(a1, ml1.y, a2 * ml2.y);
  const float o1 = bf2f(opart[(int64_t)rid * DD + lane]);
  const float o2 = bf2f(opart[((int64_t)HH * SS + rid) * DD + lane]);
  a_ws[(int64_t)q * (HH * DD) + h * DD + lane] =
      f2bf((a1 * o1 + a2 * o2) * inv);
}

extern "C" void kernel_launch(void* const* d_in, const int* in_sizes, int n_in,
                              void* d_out, int out_size, void* d_ws, size_t ws_size,
                              hipStream_t stream) {
  const float* x  = (const float*)d_in[0];
  const float* wq = (const float*)d_in[1];
  const float* wk = (const float*)d_in[2];
  const float* wv = (const float*)d_in[3];
  const float* wo = (const float*)d_in[4];
  char* ws = (char*)d_ws;
  const int64_t Mi = 1 << 20;
  // phase 1 (convert + QKV GEMM):
  u16* xb    = (u16*)(ws + 0 * Mi);    // 0-4 MiB   (dead after QKV GEMM)
  u16* wqkv  = (u16*)(ws + 4 * Mi);    // 4-10 MiB  (dead after QKV GEMM)
  u16* q_ws  = (u16*)(ws + 12 * Mi);   // 12-16 MiB (dead after attn)
  u16* k_ws  = (u16*)(ws + 16 * Mi);   // 16-20 MiB (dead after attn)
  u16* vt    = (u16*)(ws + 20 * Mi);   // 20-24 MiB (dead after attn)
  u16* wob   = (u16*)(ws + 24 * Mi);   // 24-26 MiB (live until out-proj)
  // phase 2 (attn partials, over the dead 0-10 MiB zone):
  u16*    opart = (u16*)(ws + 0 * Mi);     // 0-8 MiB  [2][16][2048][64] bf16
  float2* mlv   = (float2*)(ws + 8 * Mi);  // 8-8.5 MiB [2][16][2048] (m,l)
  // phase 3 (combine out, over dead q_ws):
  u16* a_ws  = (u16*)(ws + 12 * Mi);   // 12-16 MiB [S][H*DV]
  float* out = (float*)d_out;

  convert_kernel<<<6144, 256, 0, stream>>>(x, wq, wk, wv, wo, xb, wqkv, wob);

  // QKV: [2048,1024] x [3072,1024]^T  (grid 24x32 = 768 blocks)
  gemm_kernel<0, 1024, 3072><<<dim3(3072 / 128, 2048 / 64), 256, 0, stream>>>(
      xb, wqkv, q_ws, k_ws, vt, nullptr);

  attn_kernel<<<dim3(SS / 64, HH, 2), 256, 0, stream>>>(q_ws, k_ws, vt, opart, mlv);

  combine_kernel<<<HH * SS / 4, 256, 0, stream>>>(opart, mlv, a_ws);

  // out-proj: [2048,1024] x [1024,1024]^T -> fp32  (grid 8x32 = 256 blocks)
  gemm_kernel<1, 1024, 1024><<<dim3(1024 / 128, 2048 / 64), 256, 0, stream>>>(
      a_ws, wob, nullptr, nullptr, nullptr, out);
}